// Round 1
// baseline (3865.862 us; speedup 1.0000x reference)
//
#include <hip/hip_runtime.h>

constexpr int NN = 50000;
constexpr int NE = 1600000;
constexpr int NG = 64;

// ---------------------------------------------------------------- histogram
__global__ void hist_kernel(const int* __restrict__ dst, int* __restrict__ counts, int n) {
    int i = blockIdx.x * blockDim.x + threadIdx.x;
    int stride = gridDim.x * blockDim.x;
    for (; i < n; i += stride) atomicAdd(&counts[dst[i]], 1);
}

// ------------------------------------------------- single-block scan (CSR ptr)
__global__ void scan_kernel(const int* __restrict__ counts, int* __restrict__ row_ptr,
                            int* __restrict__ cursor, int n) {
    __shared__ int wsum[4];
    __shared__ int carry_s;
    int tid = threadIdx.x;
    int lane = tid & 63;
    int wid = tid >> 6;
    if (tid == 0) carry_s = 0;
    __syncthreads();
    for (int base = 0; base < n; base += 256) {
        int i = base + tid;
        int c = (i < n) ? counts[i] : 0;
        // wave-inclusive scan (shfl, no barriers)
        int v = c;
        #pragma unroll
        for (int s = 1; s < 64; s <<= 1) {
            int u = __shfl_up(v, s);
            if (lane >= s) v += u;
        }
        if (lane == 63) wsum[wid] = v;
        __syncthreads();
        int woff = 0;
        #pragma unroll
        for (int w = 0; w < 4; ++w) if (w < wid) woff += wsum[w];
        int excl = carry_s + woff + v - c;
        if (i < n) { row_ptr[i] = excl; cursor[i] = excl; }
        __syncthreads();   // everyone has read carry_s / wsum
        if (tid == 0) carry_s += wsum[0] + wsum[1] + wsum[2] + wsum[3];
        __syncthreads();
    }
    if (tid == 0) row_ptr[n] = carry_s;
}

// ---------------------------------------------------------------- CSR fill
__global__ void fill_kernel(const int* __restrict__ src, const int* __restrict__ dst,
                            int* __restrict__ cursor, int* __restrict__ csr_src, int n) {
    int i = blockIdx.x * blockDim.x + threadIdx.x;
    int stride = gridDim.x * blockDim.x;
    for (; i < n; i += stride) {
        int p = atomicAdd(&cursor[dst[i]], 1);
        csr_src[p] = src[i];
    }
}

// ---------------------------------------------------------------- dinv
__global__ void dinv_kernel(const int* __restrict__ counts, float* __restrict__ dinv, int n) {
    int i = blockIdx.x * blockDim.x + threadIdx.x;
    if (i < n) dinv[i] = rsqrtf((float)(counts[i] + 1));
}

// ------------------------------------------- GEMM: G = (A @ W) * dinv[row]
// A: [M][K] row-major, W: [K][N] row-major, G: [M][N]. K % 16 == 0, N % 4 == 0.
__global__ __launch_bounds__(256)
void gemm_scaled_kernel(const float* __restrict__ A, const float* __restrict__ W,
                        const float* __restrict__ dinv, float* __restrict__ G,
                        int M, int N, int K) {
    __shared__ float As[16][64];   // [k][m]
    __shared__ float Bs[16][64];   // [k][n]
    int tid = threadIdx.x;
    int tx = tid & 15, ty = tid >> 4;
    int row0 = blockIdx.x * 64;
    int col0 = blockIdx.y * 64;
    float acc[4][4] = {};

    int arow = tid >> 2, akq = tid & 3;          // A tile: 64 rows x 4 float4
    int brow = tid >> 4, bc = (tid & 15) * 4;    // B tile: 16 k-rows x 16 float4

    for (int k0 = 0; k0 < K; k0 += 16) {
        float4 av = make_float4(0.f, 0.f, 0.f, 0.f);
        int gr = row0 + arow;
        if (gr < M) av = *(const float4*)&A[(size_t)gr * K + k0 + akq * 4];
        As[akq * 4 + 0][arow] = av.x;
        As[akq * 4 + 1][arow] = av.y;
        As[akq * 4 + 2][arow] = av.z;
        As[akq * 4 + 3][arow] = av.w;

        float4 bv = make_float4(0.f, 0.f, 0.f, 0.f);
        if (col0 + bc < N) bv = *(const float4*)&W[(size_t)(k0 + brow) * N + col0 + bc];
        *(float4*)&Bs[brow][bc] = bv;
        __syncthreads();

        #pragma unroll
        for (int kk = 0; kk < 16; ++kk) {
            float4 a4 = *(const float4*)&As[kk][ty * 4];
            float4 b4 = *(const float4*)&Bs[kk][tx * 4];
            float a[4] = {a4.x, a4.y, a4.z, a4.w};
            float b[4] = {b4.x, b4.y, b4.z, b4.w};
            #pragma unroll
            for (int i2 = 0; i2 < 4; ++i2)
                #pragma unroll
                for (int j2 = 0; j2 < 4; ++j2)
                    acc[i2][j2] = fmaf(a[i2], b[j2], acc[i2][j2]);
        }
        __syncthreads();
    }

    #pragma unroll
    for (int i2 = 0; i2 < 4; ++i2) {
        int r = row0 + ty * 4 + i2;
        int c = col0 + tx * 4;
        if (r < M && c < N) {
            float dv = dinv[r];
            float4 o;
            o.x = acc[i2][0] * dv; o.y = acc[i2][1] * dv;
            o.z = acc[i2][2] * dv; o.w = acc[i2][3] * dv;
            *(float4*)&G[(size_t)r * N + c] = o;
        }
    }
}

// ---------------- aggregation: Hout[i] = act(dinv[i]*(g[i] + sum g[src]) + b)
// one 64-lane wave per (node, 64-col chunk)
__global__ __launch_bounds__(256)
void agg_kernel(const float* __restrict__ G, const int* __restrict__ row_ptr,
                const int* __restrict__ csr_src, const float* __restrict__ dinv,
                const float* __restrict__ bias, float* __restrict__ Hout,
                int nwaves, int chunks_per_node, int W, int act) {
    int wid = blockIdx.x * (blockDim.x >> 6) + (threadIdx.x >> 6);
    if (wid >= nwaves) return;
    int lane = threadIdx.x & 63;
    int node = wid / chunks_per_node;
    int chunk = wid - node * chunks_per_node;
    int col = chunk * 64 + lane;
    if (col >= W) return;

    float acc = G[(size_t)node * W + col];   // self-loop term
    int e0 = row_ptr[node], e1 = row_ptr[node + 1];
    for (int base = e0; base < e1; base += 64) {
        int cnt = min(64, e1 - base);
        int ed = (base + lane < e1) ? csr_src[base + lane] : 0;
        int j = 0;
        for (; j + 4 <= cnt; j += 4) {
            int s0 = __shfl(ed, j + 0);
            int s1 = __shfl(ed, j + 1);
            int s2 = __shfl(ed, j + 2);
            int s3 = __shfl(ed, j + 3);
            float v0 = G[(size_t)s0 * W + col];
            float v1 = G[(size_t)s1 * W + col];
            float v2 = G[(size_t)s2 * W + col];
            float v3 = G[(size_t)s3 * W + col];
            acc += v0 + v1 + v2 + v3;
        }
        for (; j < cnt; ++j) {
            int s = __shfl(ed, j);
            acc += G[(size_t)s * W + col];
        }
    }
    float out = fmaf(acc, dinv[node], bias[col]);
    if (act == 1) out = fmaxf(out, 0.f);
    else if (act == 2) out = (out > 0.f) ? out : 0.01f * out;
    Hout[(size_t)node * W + col] = out;
}

// ---------------------------------------------------------------- mean pool
__global__ __launch_bounds__(256)
void pool_kernel(const float* __restrict__ H, const int* __restrict__ batch,
                 float* __restrict__ out) {
    int g = blockIdx.x;
    // lower_bound(g), lower_bound(g+1) over sorted batch
    int lo = 0, hi = NN;
    while (lo < hi) { int mid = (lo + hi) >> 1; if (batch[mid] < g) lo = mid + 1; else hi = mid; }
    int start = lo;
    lo = start; hi = NN;
    while (lo < hi) { int mid = (lo + hi) >> 1; if (batch[mid] < g + 1) lo = mid + 1; else hi = mid; }
    int end = lo;

    int col = threadIdx.x & 31, part = threadIdx.x >> 5;  // 8 partitions x 32 cols
    float acc = 0.f;
    for (int n = start + part; n < end; n += 8)
        acc += H[(size_t)n * 32 + col];
    __shared__ float lds[256];
    lds[threadIdx.x] = acc;
    __syncthreads();
    if (part == 0) {
        float s = 0.f;
        #pragma unroll
        for (int p = 0; p < 8; ++p) s += lds[p * 32 + col];
        int cnt = end - start;
        out[g * 32 + col] = s / (float)max(cnt, 1);
    }
}

// ---------------------------------------------------------------------------
extern "C" void kernel_launch(void* const* d_in, const int* in_sizes, int n_in,
                              void* d_out, int out_size, void* d_ws, size_t ws_size,
                              hipStream_t stream) {
    const float* x     = (const float*)d_in[0];
    const int*   eidx  = (const int*)d_in[1];
    const int*   batch = (const int*)d_in[2];
    const float* Wt[9];
    const float* bt[9];
    for (int i = 0; i < 9; ++i) {
        Wt[i] = (const float*)d_in[3 + 2 * i];
        bt[i] = (const float*)d_in[4 + 2 * i];
    }
    const int widths[10] = {128, 128, 256, 384, 512, 512, 384, 256, 128, 32};
    const int acts[9]    = {1, 1, 2, 1, 2, 2, 1, 1, 0};

    char* ws = (char*)d_ws;
    size_t off = 0;
    auto alloc = [&](size_t bytes) {
        void* p = ws + off;
        off += (bytes + 255) / 256 * 256;
        return p;
    };
    float* bufA    = (float*)alloc((size_t)NN * 512 * 4);  // h buffer
    float* bufB    = (float*)alloc((size_t)NN * 512 * 4);  // g buffer
    int*   csr_src = (int*)alloc((size_t)NE * 4);
    int*   row_ptr = (int*)alloc((size_t)(NN + 1) * 4);
    int*   cursor  = (int*)alloc((size_t)NN * 4);
    int*   counts  = (int*)alloc((size_t)NN * 4);
    float* dinv    = (float*)alloc((size_t)NN * 4);

    const int* src = eidx;
    const int* dst = eidx + NE;

    hipMemsetAsync(counts, 0, (size_t)NN * 4, stream);
    hist_kernel<<<4096, 256, 0, stream>>>(dst, counts, NE);
    scan_kernel<<<1, 256, 0, stream>>>(counts, row_ptr, cursor, NN);
    fill_kernel<<<4096, 256, 0, stream>>>(src, dst, cursor, csr_src, NE);
    dinv_kernel<<<(NN + 255) / 256, 256, 0, stream>>>(counts, dinv, NN);

    const float* h = x;
    for (int l = 0; l < 9; ++l) {
        int K = widths[l], N = widths[l + 1];
        dim3 gg((NN + 63) / 64, (N + 63) / 64);
        gemm_scaled_kernel<<<gg, 256, 0, stream>>>(h, Wt[l], dinv, bufB, NN, N, K);
        int cpn = (N + 63) / 64;
        int nw = NN * cpn;
        agg_kernel<<<(nw + 3) / 4, 256, 0, stream>>>(bufB, row_ptr, csr_src, dinv,
                                                     bt[l], bufA, nw, cpn, N, acts[l]);
        h = bufA;
    }

    pool_kernel<<<NG, 256, 0, stream>>>(bufA, batch, (float*)d_out);
}

// Round 3
// 1801.229 us; speedup vs baseline: 2.1462x; 2.1462x over previous
//
#include <hip/hip_runtime.h>

using u16 = unsigned short;
using u32 = unsigned int;
typedef __attribute__((ext_vector_type(4))) float f32x4;
typedef __attribute__((ext_vector_type(8))) short bf16x8;

constexpr int NN = 50000;
constexpr int NE = 1600000;
constexpr int NG = 64;

__device__ inline u16 f2bf(float f) {
    u32 u = __builtin_bit_cast(u32, f);
    u += 0x7fff + ((u >> 16) & 1);
    return (u16)(u >> 16);
}
__device__ inline float bf2f(u32 hi16) { return __builtin_bit_cast(float, hi16 << 16); }
__device__ inline u32 packbf(float x, float y) { return (u32)f2bf(x) | ((u32)f2bf(y) << 16); }

// ---------------------------------------------------------------- histogram
__global__ void hist_kernel(const int* __restrict__ dst, int* __restrict__ counts, int n) {
    int i = blockIdx.x * blockDim.x + threadIdx.x;
    int stride = gridDim.x * blockDim.x;
    for (; i < n; i += stride) atomicAdd(&counts[dst[i]], 1);
}

// ------------------------------------------------- single-block scan (CSR ptr)
__global__ void scan_kernel(const int* __restrict__ counts, int* __restrict__ row_ptr,
                            int* __restrict__ cursor, int n) {
    __shared__ int wsum[4];
    __shared__ int carry_s;
    int tid = threadIdx.x;
    int lane = tid & 63;
    int wid = tid >> 6;
    if (tid == 0) carry_s = 0;
    __syncthreads();
    for (int base = 0; base < n; base += 256) {
        int i = base + tid;
        int c = (i < n) ? counts[i] : 0;
        int v = c;
        #pragma unroll
        for (int s = 1; s < 64; s <<= 1) {
            int u = __shfl_up(v, s);
            if (lane >= s) v += u;
        }
        if (lane == 63) wsum[wid] = v;
        __syncthreads();
        int woff = 0;
        #pragma unroll
        for (int w = 0; w < 4; ++w) if (w < wid) woff += wsum[w];
        int excl = carry_s + woff + v - c;
        if (i < n) { row_ptr[i] = excl; cursor[i] = excl; }
        __syncthreads();
        if (tid == 0) carry_s += wsum[0] + wsum[1] + wsum[2] + wsum[3];
        __syncthreads();
    }
    if (tid == 0) row_ptr[n] = carry_s;
}

// ---------------------------------------------------------------- CSR fill
__global__ void fill_kernel(const int* __restrict__ src, const int* __restrict__ dst,
                            int* __restrict__ cursor, int* __restrict__ csr_src, int n) {
    int i = blockIdx.x * blockDim.x + threadIdx.x;
    int stride = gridDim.x * blockDim.x;
    for (; i < n; i += stride) {
        int p = atomicAdd(&cursor[dst[i]], 1);
        csr_src[p] = src[i];
    }
}

// ---------------------------------------------------------------- dinv
__global__ void dinv_kernel(const int* __restrict__ counts, float* __restrict__ dinv, int n) {
    int i = blockIdx.x * blockDim.x + threadIdx.x;
    if (i < n) dinv[i] = rsqrtf((float)(counts[i] + 1));
}

// ---------------------------------------------------------------- converts
__global__ void cvt_x_kernel(const float* __restrict__ x, u32* __restrict__ xb, int npairs) {
    int i = blockIdx.x * blockDim.x + threadIdx.x;
    if (i < npairs) {
        float2 v = *(const float2*)&x[2 * i];
        xb[i] = packbf(v.x, v.y);
    }
}
// Wt[n][k] = bf16(W[k][n])
__global__ void cvt_w_kernel(const float* __restrict__ W, u16* __restrict__ Wt, int K, int N) {
    int t = blockIdx.x * blockDim.x + threadIdx.x;
    if (t < K * N) {
        int n = t / K, k = t - n * K;
        Wt[t] = f2bf(W[(size_t)k * N + n]);
    }
}

// ------------------------------------------- MFMA GEMM: Out = epi(A @ Wt^T)
// A: [M][K] bf16 row-major. Bt: [N][K] bf16 (transposed weights). Out: [M][N] bf16.
// EPI 0: Out = (A@W) * dinv[row]        (transform-first, no bias)
// EPI 1: Out = relu((A@W) + bias[col])  (aggregate-first)
// EPI 2: Out = leaky((A@W) + bias[col])
template<int EPI>
__global__ __launch_bounds__(256)
void gemm_mfma(const u16* __restrict__ A, const u16* __restrict__ Bt,
               const float* __restrict__ dinv, const float* __restrict__ bias,
               u16* __restrict__ Out, int M, int N, int K) {
    __shared__ char smem[16384 + 8192];   // A tile 128x64 bf16, B tile 64x64 bf16
    const int tid = threadIdx.x;
    const int lane = tid & 63, wid = tid >> 6;
    const int wm = wid >> 1, wn = wid & 1;
    const int row0 = blockIdx.x * 128, col0 = blockIdx.y * 64;
    const int l15 = lane & 15, lg = lane >> 4;

    f32x4 acc[4][2] = {};

    for (int k0 = 0; k0 < K; k0 += 64) {
        #pragma unroll
        for (int i = 0; i < 4; ++i) {           // stage A: 4x 16B chunks/thread
            int c = tid * 4 + i;
            int r = c >> 3, kc = c & 7;
            uint4 v = make_uint4(0, 0, 0, 0);
            int gr = row0 + r;
            if (gr < M) v = *(const uint4*)&A[(size_t)gr * K + k0 + kc * 8];
            *(uint4*)&smem[r * 128 + ((kc * 16) ^ ((r & 7) << 4))] = v;
        }
        #pragma unroll
        for (int i = 0; i < 2; ++i) {           // stage B: 2x 16B chunks/thread
            int c = tid * 2 + i;
            int n = c >> 3, kc = c & 7;
            uint4 v = make_uint4(0, 0, 0, 0);
            int gn = col0 + n;
            if (gn < N) v = *(const uint4*)&Bt[(size_t)gn * K + k0 + kc * 8];
            *(uint4*)&smem[16384 + n * 128 + ((kc * 16) ^ ((n & 7) << 4))] = v;
        }
        __syncthreads();
        #pragma unroll
        for (int ks = 0; ks < 2; ++ks) {
            bf16x8 a[4], b[2];
            #pragma unroll
            for (int fm = 0; fm < 4; ++fm) {
                int r = wm * 64 + fm * 16 + l15;
                int chunk = ks * 4 + lg;
                a[fm] = *(const bf16x8*)&smem[r * 128 + ((chunk * 16) ^ ((r & 7) << 4))];
            }
            #pragma unroll
            for (int fn = 0; fn < 2; ++fn) {
                int n = wn * 32 + fn * 16 + l15;
                int chunk = ks * 4 + lg;
                b[fn] = *(const bf16x8*)&smem[16384 + n * 128 + ((chunk * 16) ^ ((n & 7) << 4))];
            }
            #pragma unroll
            for (int fm = 0; fm < 4; ++fm)
                #pragma unroll
                for (int fn = 0; fn < 2; ++fn)
                    acc[fm][fn] = __builtin_amdgcn_mfma_f32_16x16x32_bf16(a[fm], b[fn], acc[fm][fn], 0, 0, 0);
        }
        __syncthreads();
    }

    #pragma unroll
    for (int fm = 0; fm < 4; ++fm) {
        #pragma unroll
        for (int r = 0; r < 4; ++r) {
            int grow = row0 + wm * 64 + fm * 16 + lg * 4 + r;
            if (grow >= M) continue;
            float dv = (EPI == 0) ? dinv[grow] : 0.f;
            #pragma unroll
            for (int fn = 0; fn < 2; ++fn) {
                int gcol = col0 + wn * 32 + fn * 16 + l15;
                if (gcol >= N) continue;
                float v = acc[fm][fn][r];
                if (EPI == 0) {
                    v *= dv;
                } else {
                    v += bias[gcol];
                    if (EPI == 1) v = fmaxf(v, 0.f);
                    else v = (v > 0.f) ? v : 0.01f * v;
                }
                Out[(size_t)grow * N + gcol] = f2bf(v);
            }
        }
    }
}

// ---------------- aggregation over CSR, bf16 in/out, 2 cols per lane
// MODE 0 (transform-first): acc = G[self] + sum G[src];  out = act(acc*dinv[i] + bias)
// MODE 1 (aggregate-first): acc = dinv[i]*h[self] + sum dinv[src]*h[src]; out = acc*dinv[i]
template<int MODE, int ACT>
__global__ __launch_bounds__(256)
void agg_kernel(const u32* __restrict__ G, const int* __restrict__ row_ptr,
                const int* __restrict__ csr_src, const float* __restrict__ dinv,
                const float* __restrict__ bias, u32* __restrict__ Hout,
                int nwaves, int cpn, int Wd2) {
    int wid = blockIdx.x * 4 + (threadIdx.x >> 6);
    if (wid >= nwaves) return;
    int lane = threadIdx.x & 63;
    int node = wid / cpn;
    int chunk = wid - node * cpn;
    int cp = chunk * 64 + lane;        // u32 (col-pair) index within row
    bool active = cp < Wd2;
    int cpc = active ? cp : 0;

    float ax, ay;
    {
        u32 u = G[(size_t)node * Wd2 + cpc];
        float lo = bf2f(u & 0xffffu), hi = bf2f(u >> 16);
        if (MODE == 1) { float dv = dinv[node]; ax = dv * lo; ay = dv * hi; }
        else { ax = lo; ay = hi; }
    }
    int e0 = row_ptr[node], e1 = row_ptr[node + 1];
    for (int base = e0; base < e1; base += 64) {
        int cnt = min(64, e1 - base);
        int idx = base + lane;
        int ed = (idx < e1) ? csr_src[idx] : 0;
        float dv = 0.f;
        if (MODE == 1) dv = (idx < e1) ? dinv[ed] : 0.f;
        int j = 0;
        for (; j + 4 <= cnt; j += 4) {
            int s0 = __shfl(ed, j + 0), s1 = __shfl(ed, j + 1);
            int s2 = __shfl(ed, j + 2), s3 = __shfl(ed, j + 3);
            u32 u0 = G[(size_t)s0 * Wd2 + cpc];
            u32 u1 = G[(size_t)s1 * Wd2 + cpc];
            u32 u2 = G[(size_t)s2 * Wd2 + cpc];
            u32 u3 = G[(size_t)s3 * Wd2 + cpc];
            if (MODE == 1) {
                float d0 = __shfl(dv, j + 0), d1 = __shfl(dv, j + 1);
                float d2 = __shfl(dv, j + 2), d3 = __shfl(dv, j + 3);
                ax = fmaf(d0, bf2f(u0 & 0xffffu), ax); ay = fmaf(d0, bf2f(u0 >> 16), ay);
                ax = fmaf(d1, bf2f(u1 & 0xffffu), ax); ay = fmaf(d1, bf2f(u1 >> 16), ay);
                ax = fmaf(d2, bf2f(u2 & 0xffffu), ax); ay = fmaf(d2, bf2f(u2 >> 16), ay);
                ax = fmaf(d3, bf2f(u3 & 0xffffu), ax); ay = fmaf(d3, bf2f(u3 >> 16), ay);
            } else {
                ax += bf2f(u0 & 0xffffu) + bf2f(u1 & 0xffffu) + bf2f(u2 & 0xffffu) + bf2f(u3 & 0xffffu);
                ay += bf2f(u0 >> 16) + bf2f(u1 >> 16) + bf2f(u2 >> 16) + bf2f(u3 >> 16);
            }
        }
        for (; j < cnt; ++j) {
            int s = __shfl(ed, j);
            u32 u = G[(size_t)s * Wd2 + cpc];
            if (MODE == 1) {
                float d = __shfl(dv, j);
                ax = fmaf(d, bf2f(u & 0xffffu), ax); ay = fmaf(d, bf2f(u >> 16), ay);
            } else {
                ax += bf2f(u & 0xffffu); ay += bf2f(u >> 16);
            }
        }
    }
    float di = dinv[node];
    float ox, oy;
    if (MODE == 1) {
        ox = ax * di; oy = ay * di;
    } else {
        ox = fmaf(ax, di, bias[2 * cpc]);
        oy = fmaf(ay, di, bias[2 * cpc + 1]);
        if (ACT == 1) { ox = fmaxf(ox, 0.f); oy = fmaxf(oy, 0.f); }
        else if (ACT == 2) {
            ox = (ox > 0.f) ? ox : 0.01f * ox;
            oy = (oy > 0.f) ? oy : 0.01f * oy;
        }
    }
    if (active) Hout[(size_t)node * Wd2 + cp] = packbf(ox, oy);
}

// ---------------------------------------------------------------- mean pool (bf16 in)
__global__ __launch_bounds__(256)
void pool_kernel(const u32* __restrict__ H, const int* __restrict__ batch,
                 float* __restrict__ out) {
    int g = blockIdx.x;
    int lo = 0, hi = NN;
    while (lo < hi) { int mid = (lo + hi) >> 1; if (batch[mid] < g) lo = mid + 1; else hi = mid; }
    int start = lo;
    lo = start; hi = NN;
    while (lo < hi) { int mid = (lo + hi) >> 1; if (batch[mid] < g + 1) lo = mid + 1; else hi = mid; }
    int end = lo;

    int cp = threadIdx.x & 15, part = threadIdx.x >> 4;   // 16 parts x 16 col-pairs
    float ax = 0.f, ay = 0.f;
    for (int n = start + part; n < end; n += 16) {
        u32 u = H[(size_t)n * 16 + cp];
        ax += bf2f(u & 0xffffu); ay += bf2f(u >> 16);
    }
    __shared__ float ldsx[256], ldsy[256];
    ldsx[threadIdx.x] = ax; ldsy[threadIdx.x] = ay;
    __syncthreads();
    if (part == 0) {
        float sx = 0.f, sy = 0.f;
        #pragma unroll
        for (int p = 0; p < 16; ++p) { sx += ldsx[p * 16 + cp]; sy += ldsy[p * 16 + cp]; }
        float inv = 1.f / (float)max(end - start, 1);
        out[g * 32 + 2 * cp] = sx * inv;
        out[g * 32 + 2 * cp + 1] = sy * inv;
    }
}

// ---------------------------------------------------------------------------
extern "C" void kernel_launch(void* const* d_in, const int* in_sizes, int n_in,
                              void* d_out, int out_size, void* d_ws, size_t ws_size,
                              hipStream_t stream) {
    const float* x     = (const float*)d_in[0];
    const int*   eidx  = (const int*)d_in[1];
    const int*   batch = (const int*)d_in[2];
    const float* Wf[9];
    const float* bt[9];
    for (int i = 0; i < 9; ++i) {
        Wf[i] = (const float*)d_in[3 + 2 * i];
        bt[i] = (const float*)d_in[4 + 2 * i];
    }
    const int widths[10] = {128, 128, 256, 384, 512, 512, 384, 256, 128, 32};

    char* ws = (char*)d_ws;
    size_t off = 0;
    auto alloc = [&](size_t bytes) {
        void* p = ws + off;
        off += (bytes + 255) / 256 * 256;
        return p;
    };
    u16* bufA    = (u16*)alloc((size_t)NN * 512 * 2);
    u16* bufB    = (u16*)alloc((size_t)NN * 512 * 2);
    u16* xb      = (u16*)alloc((size_t)NN * 128 * 2);
    u16* Wt[9];
    for (int i = 0; i < 9; ++i) Wt[i] = (u16*)alloc((size_t)widths[i] * widths[i + 1] * 2);
    int*   csr_src = (int*)alloc((size_t)NE * 4);
    int*   row_ptr = (int*)alloc((size_t)(NN + 1) * 4);
    int*   cursor  = (int*)alloc((size_t)NN * 4);
    int*   counts  = (int*)alloc((size_t)NN * 4);
    float* dinv    = (float*)alloc((size_t)NN * 4);

    const int* src = eidx;
    const int* dst = eidx + NE;

    hipMemsetAsync(counts, 0, (size_t)NN * 4, stream);
    hist_kernel<<<4096, 256, 0, stream>>>(dst, counts, NE);
    scan_kernel<<<1, 256, 0, stream>>>(counts, row_ptr, cursor, NN);
    fill_kernel<<<4096, 256, 0, stream>>>(src, dst, cursor, csr_src, NE);
    dinv_kernel<<<(NN + 255) / 256, 256, 0, stream>>>(counts, dinv, NN);
    cvt_x_kernel<<<(NN * 64 + 255) / 256, 256, 0, stream>>>(x, (u32*)xb, NN * 64);
    for (int i = 0; i < 9; ++i) {
        int kn = widths[i] * widths[i + 1];
        cvt_w_kernel<<<(kn + 255) / 256, 256, 0, stream>>>(Wf[i], Wt[i], widths[i], widths[i + 1]);
    }

    auto gemm = [&](int epi, const u16* A, const u16* B, const float* bias, u16* O, int N, int K) {
        dim3 g((NN + 127) / 128, (N + 63) / 64);
        if (epi == 0)      gemm_mfma<0><<<g, 256, 0, stream>>>(A, B, dinv, bias, O, NN, N, K);
        else if (epi == 1) gemm_mfma<1><<<g, 256, 0, stream>>>(A, B, dinv, bias, O, NN, N, K);
        else               gemm_mfma<2><<<g, 256, 0, stream>>>(A, B, dinv, bias, O, NN, N, K);
    };
    auto agg = [&](int mode, int act, const u16* G, const float* bias, u16* H, int W) {
        int cpn = (W / 2 + 63) / 64;
        int nw = NN * cpn;
        dim3 g((nw + 3) / 4);
        if (mode == 1)      agg_kernel<1, 0><<<g, 256, 0, stream>>>((const u32*)G, row_ptr, csr_src, dinv, bias, (u32*)H, nw, cpn, W / 2);
        else if (act == 0)  agg_kernel<0, 0><<<g, 256, 0, stream>>>((const u32*)G, row_ptr, csr_src, dinv, bias, (u32*)H, nw, cpn, W / 2);
        else if (act == 1)  agg_kernel<0, 1><<<g, 256, 0, stream>>>((const u32*)G, row_ptr, csr_src, dinv, bias, (u32*)H, nw, cpn, W / 2);
        else                agg_kernel<0, 2><<<g, 256, 0, stream>>>((const u32*)G, row_ptr, csr_src, dinv, bias, (u32*)H, nw, cpn, W / 2);
    };

    // L1: 128->128 relu, transform-first
    gemm(0, xb, Wt[0], nullptr, bufB, 128, 128);
    agg(0, 1, bufB, bt[0], bufA, 128);
    // L2: 128->256 relu, aggregate-first
    agg(1, 0, bufA, nullptr, bufB, 128);
    gemm(1, bufB, Wt[1], bt[1], bufA, 256, 128);
    // L3: 256->384 leaky, aggregate-first
    agg(1, 0, bufA, nullptr, bufB, 256);
    gemm(2, bufB, Wt[2], bt[2], bufA, 384, 256);
    // L4: 384->512 relu, aggregate-first
    agg(1, 0, bufA, nullptr, bufB, 384);
    gemm(1, bufB, Wt[3], bt[3], bufA, 512, 384);
    // L5: 512->512 leaky, transform-first
    gemm(0, bufA, Wt[4], nullptr, bufB, 512, 512);
    agg(0, 2, bufB, bt[4], bufA, 512);
    // L6: 512->384 leaky, transform-first
    gemm(0, bufA, Wt[5], nullptr, bufB, 384, 512);
    agg(0, 2, bufB, bt[5], bufA, 384);
    // L7: 384->256 relu, transform-first
    gemm(0, bufA, Wt[6], nullptr, bufB, 256, 384);
    agg(0, 1, bufB, bt[6], bufA, 256);
    // L8: 256->128 relu, transform-first
    gemm(0, bufA, Wt[7], nullptr, bufB, 128, 256);
    agg(0, 1, bufB, bt[7], bufA, 128);
    // L9: 128->32 none, transform-first
    gemm(0, bufA, Wt[8], nullptr, bufB, 32, 128);
    agg(0, 0, bufB, bt[8], bufA, 32);

    pool_kernel<<<NG, 256, 0, stream>>>((const u32*)bufA, batch, (float*)d_out);
}

// Round 4
// 1660.644 us; speedup vs baseline: 2.3279x; 1.0847x over previous
//
#include <hip/hip_runtime.h>

using u16 = unsigned short;
using u32 = unsigned int;
typedef __attribute__((ext_vector_type(4))) float f32x4;
typedef __attribute__((ext_vector_type(8))) short bf16x8;

constexpr int NN = 50000;
constexpr int NE = 1600000;
constexpr int NG = 64;

// Feature buffers are CHUNK-MAJOR: width W bf16 cols = Wd2 u32 col-pairs,
// CS = min(64, Wd2) u32 per row-chunk, cpn = Wd2/CS chunks.
// u32 index of (node, cp): chunk = cp/CS; idx = chunk*NN*CS + node*CS + cp%CS.
// For all GEMM A/Out widths here, CS=64 except W=32 (CS=16, cpn=1).

__device__ inline u16 f2bf(float f) {
    u32 u = __builtin_bit_cast(u32, f);
    u += 0x7fff + ((u >> 16) & 1);
    return (u16)(u >> 16);
}
__device__ inline float bf2f(u32 hi16) { return __builtin_bit_cast(float, hi16 << 16); }
__device__ inline u32 packbf(float x, float y) { return (u32)f2bf(x) | ((u32)f2bf(y) << 16); }

// ---------------------------------------------------------------- histogram
__global__ void hist_kernel(const int* __restrict__ dst, int* __restrict__ counts, int n) {
    int i = blockIdx.x * blockDim.x + threadIdx.x;
    int stride = gridDim.x * blockDim.x;
    for (; i < n; i += stride) atomicAdd(&counts[dst[i]], 1);
}

// ------------------------------------------------- single-block scan (CSR ptr)
__global__ void scan_kernel(const int* __restrict__ counts, int* __restrict__ row_ptr,
                            int* __restrict__ cursor, int n) {
    __shared__ int wsum[4];
    __shared__ int carry_s;
    int tid = threadIdx.x;
    int lane = tid & 63;
    int wid = tid >> 6;
    if (tid == 0) carry_s = 0;
    __syncthreads();
    for (int base = 0; base < n; base += 256) {
        int i = base + tid;
        int c = (i < n) ? counts[i] : 0;
        int v = c;
        #pragma unroll
        for (int s = 1; s < 64; s <<= 1) {
            int u = __shfl_up(v, s);
            if (lane >= s) v += u;
        }
        if (lane == 63) wsum[wid] = v;
        __syncthreads();
        int woff = 0;
        #pragma unroll
        for (int w = 0; w < 4; ++w) if (w < wid) woff += wsum[w];
        int excl = carry_s + woff + v - c;
        if (i < n) { row_ptr[i] = excl; cursor[i] = excl; }
        __syncthreads();
        if (tid == 0) carry_s += wsum[0] + wsum[1] + wsum[2] + wsum[3];
        __syncthreads();
    }
    if (tid == 0) row_ptr[n] = carry_s;
}

// ---------------------------------------------------------------- CSR fill
__global__ void fill_kernel(const int* __restrict__ src, const int* __restrict__ dst,
                            int* __restrict__ cursor, int* __restrict__ csr_src, int n) {
    int i = blockIdx.x * blockDim.x + threadIdx.x;
    int stride = gridDim.x * blockDim.x;
    for (; i < n; i += stride) {
        int p = atomicAdd(&cursor[dst[i]], 1);
        csr_src[p] = src[i];
    }
}

// ---------------------------------------------------------------- dinv
__global__ void dinv_kernel(const int* __restrict__ counts, float* __restrict__ dinv, int n) {
    int i = blockIdx.x * blockDim.x + threadIdx.x;
    if (i < n) dinv[i] = rsqrtf((float)(counts[i] + 1));
}

// ---------------------------------------------------------------- converts
__global__ void cvt_x_kernel(const float* __restrict__ x, u32* __restrict__ xb, int npairs) {
    int i = blockIdx.x * blockDim.x + threadIdx.x;
    if (i < npairs) {
        float2 v = *(const float2*)&x[2 * i];
        xb[i] = packbf(v.x, v.y);
    }
}
// Wt[n][k] = bf16(W[k][n])
__global__ void cvt_w_kernel(const float* __restrict__ W, u16* __restrict__ Wt, int K, int N) {
    int t = blockIdx.x * blockDim.x + threadIdx.x;
    if (t < K * N) {
        int n = t / K, k = t - n * K;
        Wt[t] = f2bf(W[(size_t)k * N + n]);
    }
}

// ------------------------------------------- MFMA GEMM: Out = epi(A @ Wt^T)
// A: [M] x K bf16, CHUNK-MAJOR (CS=64 u32 -> 128 cols per chunk; K multiple of 64).
// Bt: [N][K] bf16 row-major (transposed weights).
// Out: [M] x N bf16, CHUNK-MAJOR with oshift = log2(cols per chunk) (7, or 5 for N=32).
// EPI 0: Out = (A@W) * dinv[row]   EPI 1: relu((A@W)+bias)   EPI 2: leaky((A@W)+bias)
template<int EPI>
__global__ __launch_bounds__(256)
void gemm_mfma(const u16* __restrict__ A, const u16* __restrict__ Bt,
               const float* __restrict__ dinv, const float* __restrict__ bias,
               u16* __restrict__ Out, int M, int N, int K, int oshift) {
    __shared__ char smem[16384 + 8192];   // A tile 128x64 bf16, B tile 64x64 bf16
    const int tid = threadIdx.x;
    const int lane = tid & 63, wid = tid >> 6;
    const int wm = wid >> 1, wn = wid & 1;
    const int row0 = blockIdx.x * 128, col0 = blockIdx.y * 64;
    const int l15 = lane & 15, lg = lane >> 4;

    f32x4 acc[4][2] = {};

    for (int k0 = 0; k0 < K; k0 += 64) {
        // A chunk-major base: chunk = k0>>7, in-chunk col offset = k0&127 (u16 units)
        const u16* Abase = A + (size_t)(k0 >> 7) * NN * 128 + (k0 & 127);
        #pragma unroll
        for (int i = 0; i < 4; ++i) {           // stage A: 4x 16B chunks/thread
            int c = tid * 4 + i;
            int r = c >> 3, kc = c & 7;
            uint4 v = make_uint4(0, 0, 0, 0);
            int gr = row0 + r;
            if (gr < M) v = *(const uint4*)&Abase[(size_t)gr * 128 + kc * 8];
            *(uint4*)&smem[r * 128 + ((kc * 16) ^ ((r & 7) << 4))] = v;
        }
        #pragma unroll
        for (int i = 0; i < 2; ++i) {           // stage B: 2x 16B chunks/thread
            int c = tid * 2 + i;
            int n = c >> 3, kc = c & 7;
            uint4 v = make_uint4(0, 0, 0, 0);
            int gn = col0 + n;
            if (gn < N) v = *(const uint4*)&Bt[(size_t)gn * K + k0 + kc * 8];
            *(uint4*)&smem[16384 + n * 128 + ((kc * 16) ^ ((n & 7) << 4))] = v;
        }
        __syncthreads();
        #pragma unroll
        for (int ks = 0; ks < 2; ++ks) {
            bf16x8 a[4], b[2];
            #pragma unroll
            for (int fm = 0; fm < 4; ++fm) {
                int r = wm * 64 + fm * 16 + l15;
                int chunk = ks * 4 + lg;
                a[fm] = *(const bf16x8*)&smem[r * 128 + ((chunk * 16) ^ ((r & 7) << 4))];
            }
            #pragma unroll
            for (int fn = 0; fn < 2; ++fn) {
                int n = wn * 32 + fn * 16 + l15;
                int chunk = ks * 4 + lg;
                b[fn] = *(const bf16x8*)&smem[16384 + n * 128 + ((chunk * 16) ^ ((n & 7) << 4))];
            }
            #pragma unroll
            for (int fm = 0; fm < 4; ++fm)
                #pragma unroll
                for (int fn = 0; fn < 2; ++fn)
                    acc[fm][fn] = __builtin_amdgcn_mfma_f32_16x16x32_bf16(a[fm], b[fn], acc[fm][fn], 0, 0, 0);
        }
        __syncthreads();
    }

    const int omask = (1 << oshift) - 1;
    #pragma unroll
    for (int fm = 0; fm < 4; ++fm) {
        #pragma unroll
        for (int r = 0; r < 4; ++r) {
            int grow = row0 + wm * 64 + fm * 16 + lg * 4 + r;
            if (grow >= M) continue;
            float dv = (EPI == 0) ? dinv[grow] : 0.f;
            #pragma unroll
            for (int fn = 0; fn < 2; ++fn) {
                int gcol = col0 + wn * 32 + fn * 16 + l15;
                if (gcol >= N) continue;
                float v = acc[fm][fn][r];
                if (EPI == 0) {
                    v *= dv;
                } else {
                    v += bias[gcol];
                    if (EPI == 1) v = fmaxf(v, 0.f);
                    else v = (v > 0.f) ? v : 0.01f * v;
                }
                size_t oidx = (((size_t)(gcol >> oshift) * NN) << oshift)
                            + ((size_t)grow << oshift) + (gcol & omask);
                Out[oidx] = f2bf(v);
            }
        }
    }
}

// ---------------- aggregation over CSR, bf16 in/out, chunk-major, phased by blockIdx.y
// MODE 0 (transform-first): acc = G[self] + sum G[src];  out = act(acc*dinv[i] + bias)
// MODE 1 (aggregate-first): acc = dinv[i]*h[self] + sum dinv[src]*h[src]; out = acc*dinv[i]
// csshift: log2(CS) where CS = u32 per row-chunk (6 normally, 4 for W=32)
template<int MODE, int ACT>
__global__ __launch_bounds__(256)
void agg_kernel(const u32* __restrict__ G, const int* __restrict__ row_ptr,
                const int* __restrict__ csr_src, const float* __restrict__ dinv,
                const float* __restrict__ bias, u32* __restrict__ Hout, int csshift) {
    int node = blockIdx.x * 4 + (threadIdx.x >> 6);
    if (node >= NN) return;
    int lane = threadIdx.x & 63;
    const int CS = 1 << csshift;
    size_t chunkbase = (size_t)blockIdx.y * NN * 64;   // blockIdx.y>0 only when CS==64
    bool active = lane < CS;
    int ln = active ? lane : 0;

    float ax, ay;
    {
        u32 u = G[chunkbase + ((size_t)node << csshift) + ln];
        float lo = bf2f(u & 0xffffu), hi = bf2f(u >> 16);
        if (MODE == 1) { float dv = dinv[node]; ax = dv * lo; ay = dv * hi; }
        else { ax = lo; ay = hi; }
    }
    int e0 = row_ptr[node], e1 = row_ptr[node + 1];
    for (int base = e0; base < e1; base += 64) {
        int cnt = min(64, e1 - base);
        int idx = base + lane;
        int ed = (idx < e1) ? csr_src[idx] : 0;
        float dvl = 0.f;
        if (MODE == 1) dvl = (idx < e1) ? dinv[ed] : 0.f;
        int j = 0;
        for (; j + 8 <= cnt; j += 8) {
            int s[8]; u32 u[8];
            #pragma unroll
            for (int t = 0; t < 8; ++t) s[t] = __shfl(ed, j + t);
            #pragma unroll
            for (int t = 0; t < 8; ++t)
                u[t] = G[chunkbase + ((size_t)s[t] << csshift) + ln];
            if (MODE == 1) {
                #pragma unroll
                for (int t = 0; t < 8; ++t) {
                    float d = __shfl(dvl, j + t);
                    ax = fmaf(d, bf2f(u[t] & 0xffffu), ax);
                    ay = fmaf(d, bf2f(u[t] >> 16), ay);
                }
            } else {
                #pragma unroll
                for (int t = 0; t < 8; ++t) {
                    ax += bf2f(u[t] & 0xffffu);
                    ay += bf2f(u[t] >> 16);
                }
            }
        }
        for (; j < cnt; ++j) {
            int s = __shfl(ed, j);
            u32 u = G[chunkbase + ((size_t)s << csshift) + ln];
            if (MODE == 1) {
                float d = __shfl(dvl, j);
                ax = fmaf(d, bf2f(u & 0xffffu), ax); ay = fmaf(d, bf2f(u >> 16), ay);
            } else {
                ax += bf2f(u & 0xffffu); ay += bf2f(u >> 16);
            }
        }
    }
    float di = dinv[node];
    float ox, oy;
    if (MODE == 1) {
        ox = ax * di; oy = ay * di;
    } else {
        int col = blockIdx.y * 128 + 2 * lane;   // valid when active
        float bx = active ? bias[col] : 0.f;
        float by = active ? bias[col + 1] : 0.f;
        ox = fmaf(ax, di, bx);
        oy = fmaf(ay, di, by);
        if (ACT == 1) { ox = fmaxf(ox, 0.f); oy = fmaxf(oy, 0.f); }
        else if (ACT == 2) {
            ox = (ox > 0.f) ? ox : 0.01f * ox;
            oy = (oy > 0.f) ? oy : 0.01f * oy;
        }
    }
    if (active) Hout[chunkbase + ((size_t)node << csshift) + lane] = packbf(ox, oy);
}

// ---------------------------------------------------------------- mean pool (bf16 in, W=32)
__global__ __launch_bounds__(256)
void pool_kernel(const u32* __restrict__ H, const int* __restrict__ batch,
                 float* __restrict__ out) {
    int g = blockIdx.x;
    int lo = 0, hi = NN;
    while (lo < hi) { int mid = (lo + hi) >> 1; if (batch[mid] < g) lo = mid + 1; else hi = mid; }
    int start = lo;
    lo = start; hi = NN;
    while (lo < hi) { int mid = (lo + hi) >> 1; if (batch[mid] < g + 1) lo = mid + 1; else hi = mid; }
    int end = lo;

    int cp = threadIdx.x & 15, part = threadIdx.x >> 4;   // 16 parts x 16 col-pairs
    float ax = 0.f, ay = 0.f;
    for (int n = start + part; n < end; n += 16) {
        u32 u = H[(size_t)n * 16 + cp];
        ax += bf2f(u & 0xffffu); ay += bf2f(u >> 16);
    }
    __shared__ float ldsx[256], ldsy[256];
    ldsx[threadIdx.x] = ax; ldsy[threadIdx.x] = ay;
    __syncthreads();
    if (part == 0) {
        float sx = 0.f, sy = 0.f;
        #pragma unroll
        for (int p = 0; p < 16; ++p) { sx += ldsx[p * 16 + cp]; sy += ldsy[p * 16 + cp]; }
        float inv = 1.f / (float)max(end - start, 1);
        out[g * 32 + 2 * cp] = sx * inv;
        out[g * 32 + 2 * cp + 1] = sy * inv;
    }
}

// ---------------------------------------------------------------------------
extern "C" void kernel_launch(void* const* d_in, const int* in_sizes, int n_in,
                              void* d_out, int out_size, void* d_ws, size_t ws_size,
                              hipStream_t stream) {
    const float* x     = (const float*)d_in[0];
    const int*   eidx  = (const int*)d_in[1];
    const int*   batch = (const int*)d_in[2];
    const float* Wf[9];
    const float* bt[9];
    for (int i = 0; i < 9; ++i) {
        Wf[i] = (const float*)d_in[3 + 2 * i];
        bt[i] = (const float*)d_in[4 + 2 * i];
    }
    const int widths[10] = {128, 128, 256, 384, 512, 512, 384, 256, 128, 32};

    char* ws = (char*)d_ws;
    size_t off = 0;
    auto alloc = [&](size_t bytes) {
        void* p = ws + off;
        off += (bytes + 255) / 256 * 256;
        return p;
    };
    u16* bufA    = (u16*)alloc((size_t)NN * 512 * 2);
    u16* bufB    = (u16*)alloc((size_t)NN * 512 * 2);
    u16* xb      = (u16*)alloc((size_t)NN * 128 * 2);
    u16* Wt[9];
    for (int i = 0; i < 9; ++i) Wt[i] = (u16*)alloc((size_t)widths[i] * widths[i + 1] * 2);
    int*   csr_src = (int*)alloc((size_t)NE * 4);
    int*   row_ptr = (int*)alloc((size_t)(NN + 1) * 4);
    int*   cursor  = (int*)alloc((size_t)NN * 4);
    int*   counts  = (int*)alloc((size_t)NN * 4);
    float* dinv    = (float*)alloc((size_t)NN * 4);

    const int* src = eidx;
    const int* dst = eidx + NE;

    hipMemsetAsync(counts, 0, (size_t)NN * 4, stream);
    hist_kernel<<<4096, 256, 0, stream>>>(dst, counts, NE);
    scan_kernel<<<1, 256, 0, stream>>>(counts, row_ptr, cursor, NN);
    fill_kernel<<<4096, 256, 0, stream>>>(src, dst, cursor, csr_src, NE);
    dinv_kernel<<<(NN + 255) / 256, 256, 0, stream>>>(counts, dinv, NN);
    cvt_x_kernel<<<(NN * 64 + 255) / 256, 256, 0, stream>>>(x, (u32*)xb, NN * 64);
    for (int i = 0; i < 9; ++i) {
        int kn = widths[i] * widths[i + 1];
        cvt_w_kernel<<<(kn + 255) / 256, 256, 0, stream>>>(Wf[i], Wt[i], widths[i], widths[i + 1]);
    }

    auto gemm = [&](int epi, const u16* A, const u16* B, const float* bias, u16* O, int N, int K) {
        dim3 g((NN + 127) / 128, (N + 63) / 64);
        int oshift = (N >= 128) ? 7 : 5;       // cols per out chunk: 128, or 32 for N=32
        if (epi == 0)      gemm_mfma<0><<<g, 256, 0, stream>>>(A, B, dinv, bias, O, NN, N, K, oshift);
        else if (epi == 1) gemm_mfma<1><<<g, 256, 0, stream>>>(A, B, dinv, bias, O, NN, N, K, oshift);
        else               gemm_mfma<2><<<g, 256, 0, stream>>>(A, B, dinv, bias, O, NN, N, K, oshift);
    };
    auto agg = [&](int mode, int act, const u16* G, const float* bias, u16* H, int W) {
        int Wd2 = W / 2;
        int cs = (Wd2 >= 64) ? 64 : Wd2;
        int csshift = (cs == 64) ? 6 : 4;
        int cpn = Wd2 / cs;
        dim3 g((NN + 3) / 4, cpn);
        if (mode == 1)      agg_kernel<1, 0><<<g, 256, 0, stream>>>((const u32*)G, row_ptr, csr_src, dinv, bias, (u32*)H, csshift);
        else if (act == 0)  agg_kernel<0, 0><<<g, 256, 0, stream>>>((const u32*)G, row_ptr, csr_src, dinv, bias, (u32*)H, csshift);
        else if (act == 1)  agg_kernel<0, 1><<<g, 256, 0, stream>>>((const u32*)G, row_ptr, csr_src, dinv, bias, (u32*)H, csshift);
        else                agg_kernel<0, 2><<<g, 256, 0, stream>>>((const u32*)G, row_ptr, csr_src, dinv, bias, (u32*)H, csshift);
    };

    // L1: 128->128 relu, transform-first
    gemm(0, xb, Wt[0], nullptr, bufB, 128, 128);
    agg(0, 1, bufB, bt[0], bufA, 128);
    // L2: 128->256 relu, aggregate-first
    agg(1, 0, bufA, nullptr, bufB, 128);
    gemm(1, bufB, Wt[1], bt[1], bufA, 256, 128);
    // L3: 256->384 leaky, aggregate-first
    agg(1, 0, bufA, nullptr, bufB, 256);
    gemm(2, bufB, Wt[2], bt[2], bufA, 384, 256);
    // L4: 384->512 relu, aggregate-first
    agg(1, 0, bufA, nullptr, bufB, 384);
    gemm(1, bufB, Wt[3], bt[3], bufA, 512, 384);
    // L5: 512->512 leaky, transform-first
    gemm(0, bufA, Wt[4], nullptr, bufB, 512, 512);
    agg(0, 2, bufB, bt[4], bufA, 512);
    // L6: 512->384 leaky, transform-first
    gemm(0, bufA, Wt[5], nullptr, bufB, 384, 512);
    agg(0, 2, bufB, bt[5], bufA, 384);
    // L7: 384->256 relu, transform-first
    gemm(0, bufA, Wt[6], nullptr, bufB, 256, 384);
    agg(0, 1, bufB, bt[6], bufA, 256);
    // L8: 256->128 relu, transform-first
    gemm(0, bufA, Wt[7], nullptr, bufB, 128, 256);
    agg(0, 1, bufB, bt[7], bufA, 128);
    // L9: 128->32 none, transform-first
    gemm(0, bufA, Wt[8], nullptr, bufB, 32, 128);
    agg(0, 0, bufB, bt[8], bufA, 32);

    pool_kernel<<<NG, 256, 0, stream>>>((const u32*)bufA, batch, (float*)d_out);
}